// Round 11
// baseline (212.664 us; speedup 1.0000x reference)
//
#include <hip/hip_runtime.h>

#define N_NODES 50000
#define E_EDGES 600000
#define IN_DIM  128
#define HID     256
#define OUT_DIM 128
#define CAP     64     // bucket capacity (deg ~ Poisson(12), max ~35); 64*4B = 256B d_out slot
#define ZROW    N_NODES   // sentinel ht row of zeros (row 50000)

#define RANGE_N 6250   // N_NODES / 8 ranges (one per XCD, heuristically)
#define NCHUNK  32     // edge chunks for CSR build
#define CHUNK_E (E_EDGES / NCHUNK)   // 18750
#define NB_HIST 256    // 8 ranges x 32 chunks (block b: r=b&7, c=b>>3)
#define NB_HCVT 3125   // N*16/256, 8 floats/thread
#define NB_WCVT 384    // (65536+32768)/256
#define NB_PREP (NB_HIST + NB_HCVT + NB_WCVT + 1)   // 3766 (last block zeroes ZROW)
#define NB_CSR  196    // ceil(50000/256)
#define NB_MLP  1563   // (N_NODES+31)/32  -- 32-row blocks
#define BROWS   32

// fallback (atomic) fill geometry — r8 proven
#define FB_CHUNK_E 2048
#define FB_NB_FILL 2344
#define FB_NB_PREP (FB_NB_FILL + NB_HCVT + NB_WCVT + 1)

typedef __bf16 bf16x8 __attribute__((ext_vector_type(8)));
typedef float  f32x16 __attribute__((ext_vector_type(16)));
typedef unsigned short ushort8 __attribute__((ext_vector_type(8)));

__device__ __forceinline__ unsigned short f2bf(float f) {
    union { float f; unsigned int i; } v; v.f = f;
    unsigned int b = v.i;
    b += 0x7fffu + ((b >> 16) & 1u);   // RNE
    return (unsigned short)(b >> 16);
}
// accumulate 2 packed bf16 (one uint) into two f32 accumulators: 4 VALU insts
__device__ __forceinline__ void acc2(unsigned u, float& a0, float& a1) {
    union { unsigned i; float f; } lo, hi;
    lo.i = u << 16; hi.i = u & 0xffff0000u;
    a0 += lo.f; a1 += hi.f;
}

// ---------------------------------------------------------------------------
// Shared cvt jobs (h fp32->bf16 into ws ht; W1/W2 -> swizzled bf16):
//   w1sw flat = (((c*4 + ks)*2 + g)*256 + n)*8 + j,  k = c*64 + ks*16 + g*8 + j
//   w2sw flat = (((c*8 + ks)*2 + g)*128 + n)*8 + j,  k = c*128 + ks*16 + g*8 + j
// d_out row n (512 B): [0,256) unused-here | [256,512) bucket int[64].
// ---------------------------------------------------------------------------
__device__ __forceinline__ void do_hcvt(int b0, int b, const float* __restrict__ h,
                                        unsigned short* __restrict__ ht) {
    int idx = (b - b0) * 256 + threadIdx.x;   // < 800000 exactly
    int n = idx >> 4, g = idx & 15;            // 16 threads/node, 8 f/thread
    const float4 v0 = *(const float4*)(h + (size_t)n * IN_DIM + g * 8);
    const float4 v1 = *(const float4*)(h + (size_t)n * IN_DIM + g * 8 + 4);
    ushort8 o;
    o[0] = f2bf(v0.x); o[1] = f2bf(v0.y); o[2] = f2bf(v0.z); o[3] = f2bf(v0.w);
    o[4] = f2bf(v1.x); o[5] = f2bf(v1.y); o[6] = f2bf(v1.z); o[7] = f2bf(v1.w);
    *(ushort8*)(ht + (size_t)n * 128 + g * 8) = o;
}
__device__ __forceinline__ void do_wcvt(int b0, int b,
                                        const float* __restrict__ W1,
                                        const float* __restrict__ W2,
                                        unsigned short* __restrict__ w1sw,
                                        unsigned short* __restrict__ w2sw) {
    int i1 = (b - b0) * 256 + threadIdx.x;
    if (i1 < 65536) {
        int j = i1 & 7, n = (i1 >> 3) & 255, g = (i1 >> 11) & 1, ks = (i1 >> 12) & 3, c = i1 >> 14;
        int k = c * 64 + ks * 16 + g * 8 + j;
        w1sw[i1] = f2bf(W1[(size_t)k * HID + n]);
    } else {
        int i2 = i1 - 65536;
        int j = i2 & 7, n = (i2 >> 3) & 127, g = (i2 >> 10) & 1, ks = (i2 >> 11) & 7, c = (i2 >> 14) & 1;
        int k = c * 128 + ks * 16 + g * 8 + j;
        w2sw[i2] = f2bf(W2[(size_t)k * OUT_DIM + n]);
    }
}

// ---------------------------------------------------------------------------
// CSR pass 1 (+cvt jobs): blocks 0..255 build per-(range,chunk) histograms in
// LDS (DS atomics only — no global atomics), dumped as u8 (per-node-per-chunk
// count <= deg <= ~35). hist8[b][nl], b = c*8+r. No memset needed anywhere:
// LDS zeroed in-kernel, hist8 fully overwritten, counts written by pass 2.
// ---------------------------------------------------------------------------
__global__ void __launch_bounds__(256)
sage_prep(const int* __restrict__ dst,
          unsigned char* __restrict__ hist8,
          const float* __restrict__ h, unsigned short* __restrict__ ht,
          const float* __restrict__ W1, const float* __restrict__ W2,
          unsigned short* __restrict__ w1sw, unsigned short* __restrict__ w2sw) {
    __shared__ unsigned lhist[RANGE_N];
    int b = blockIdx.x;
    if (b < NB_HIST) {
        int r = b & 7, c = b >> 3;
        for (int i = threadIdx.x; i < RANGE_N; i += 256) lhist[i] = 0u;
        __syncthreads();
        int lo = r * RANGE_N;
        int e0 = c * CHUNK_E, e1 = e0 + CHUNK_E;
        for (int e = e0 + threadIdx.x; e < e1; e += 256) {
            int d = dst[e] - lo;
            if ((unsigned)d < (unsigned)RANGE_N)
                atomicAdd(&lhist[d], 1u);
        }
        __syncthreads();
        unsigned char* hb = hist8 + (size_t)b * RANGE_N;
        for (int i = threadIdx.x; i < RANGE_N; i += 256)
            hb[i] = (unsigned char)min(lhist[i], 255u);
    } else if (b < NB_HIST + NB_HCVT) {
        do_hcvt(NB_HIST, b, h, ht);
    } else if (b < NB_HIST + NB_HCVT + NB_WCVT) {
        do_wcvt(NB_HIST + NB_HCVT, b, W1, W2, w1sw, w2sw);
    } else {
        if (threadIdx.x < 64)
            *(unsigned*)(ht + (size_t)ZROW * 128 + threadIdx.x * 2) = 0u;
    }
}

// ---------------------------------------------------------------------------
// CSR pass 2: per node, exclusive prefix of the 32 chunk-counts (in place)
// + total -> counts[n]. Coalesced: consecutive threads = consecutive nl.
// ---------------------------------------------------------------------------
__global__ void __launch_bounds__(256)
sage_csr(unsigned char* __restrict__ hist8, int* __restrict__ counts) {
    int n = blockIdx.x * 256 + threadIdx.x;
    if (n >= N_NODES) return;
    int r = n / RANGE_N, nl = n - r * RANGE_N;
    unsigned acc = 0;
    #pragma unroll
    for (int c = 0; c < NCHUNK; ++c) {
        size_t idx = (size_t)(c * 8 + r) * RANGE_N + nl;
        unsigned v = hist8[idx];
        hist8[idx] = (unsigned char)acc;   // exclusive prefix (deg <= 255 safe)
        acc += v;
    }
    counts[n] = (int)acc;
}

// ---------------------------------------------------------------------------
// CSR pass 3: atomic-free scatter. Block b (= c*8+r) re-scans its chunk; for
// in-range edges slot = pref (u8, L1-hot 6.25KB window) + LDS cursor++ (DS
// atomic). Only the unavoidable 600k scattered stores hit global. Slots are
// contiguous 0..deg-1; slot>=CAP dropped (P ~ 1e-30 at lambda=12), matching
// the old CAP behavior (mean still divides by full deg).
// ---------------------------------------------------------------------------
__global__ void __launch_bounds__(256)
sage_fill(const int* __restrict__ src, const int* __restrict__ dst,
          const unsigned char* __restrict__ hist8, char* __restrict__ outb) {
    __shared__ unsigned lcur[RANGE_N];
    int b = blockIdx.x;
    int r = b & 7, c = b >> 3;
    for (int i = threadIdx.x; i < RANGE_N; i += 256) lcur[i] = 0u;
    __syncthreads();
    int lo = r * RANGE_N;
    int e0 = c * CHUNK_E, e1 = e0 + CHUNK_E;
    const unsigned char* hb = hist8 + (size_t)b * RANGE_N;
    for (int e = e0 + threadIdx.x; e < e1; e += 256) {
        int d = dst[e];
        int dl = d - lo;
        if ((unsigned)dl < (unsigned)RANGE_N) {
            int s = src[e];
            unsigned slot = (unsigned)hb[dl] + atomicAdd(&lcur[dl], 1u);
            if (slot < CAP)
                *((int*)(outb + (size_t)d * 512 + 256) + slot) = s;
        }
    }
}

// ---------------------------------------------------------------------------
// FALLBACK prep (r8 proven): atomic fill + cvt + sentinel, used when ws is
// too small for the hist buffer. Requires counts pre-zeroed (host memset).
// ---------------------------------------------------------------------------
__global__ void __launch_bounds__(256)
sage_prep_fb(const int* __restrict__ src, const int* __restrict__ dst,
             int* __restrict__ counts, char* __restrict__ outb,
             const float* __restrict__ h, unsigned short* __restrict__ ht,
             const float* __restrict__ W1, const float* __restrict__ W2,
             unsigned short* __restrict__ w1sw, unsigned short* __restrict__ w2sw) {
    int b = blockIdx.x;
    if (b < FB_NB_FILL) {
        int r = b & 7;
        int chunk = b >> 3;
        int e0 = chunk * FB_CHUNK_E + threadIdx.x * 8;
        if (e0 < E_EDGES) {
            int lo = r * RANGE_N, hi = lo + RANGE_N;
            const int4 d0 = *(const int4*)(dst + e0);
            const int4 d1 = *(const int4*)(dst + e0 + 4);
            int dd[8] = {d0.x, d0.y, d0.z, d0.w, d1.x, d1.y, d1.z, d1.w};
            #pragma unroll
            for (int k = 0; k < 8; ++k) {
                int d = dd[k];
                if (d >= lo && d < hi) {
                    int s = src[e0 + k];
                    int sl = atomicAdd(counts + d, 1);
                    if (sl < CAP) *((int*)(outb + (size_t)d * 512 + 256) + sl) = s;
                }
            }
        }
    } else if (b < FB_NB_FILL + NB_HCVT) {
        do_hcvt(FB_NB_FILL, b, h, ht);
    } else if (b < FB_NB_FILL + NB_HCVT + NB_WCVT) {
        do_wcvt(FB_NB_FILL + NB_HCVT, b, W1, W2, w1sw, w2sw);
    } else {
        if (threadIdx.x < 64)
            *(unsigned*)(ht + (size_t)ZROW * 128 + threadIdx.x * 2) = 0u;
    }
}

// ---------------------------------------------------------------------------
// Fused gather + 2-layer MLP — r8 structure verbatim (32-row blocks, 8/CU,
// branch-free sentinel gather, contiguous bucket slots, single counts).
// ---------------------------------------------------------------------------
__global__ void __launch_bounds__(256, 8)
sage_fused(const int* __restrict__ counts,
           const unsigned short* __restrict__ ht,     // ws: bf16 [N+1][128]
           const unsigned short* __restrict__ w1sw,
           const unsigned short* __restrict__ w2sw,
           const float* __restrict__ b1,
           const float* __restrict__ b2,
           float* out) {                              // d_out (also holds bucket)
    __shared__ unsigned short hid_s[BROWS][264];  // 16.9 KB: [0:128)=means, [128:256)=self

    const int t = threadIdx.x;
    const int nw = t >> 6;
    const int lane = t & 63;
    const int lr = lane & 31;
    const int lg = lane >> 5;
    const int base = blockIdx.x * BROWS;

    // ---- Phase G: branch-free coalesced gather, 8 nodes/wave (2 groups) ----
    {
        #pragma unroll 1
        for (int g = 0; g < 2; ++g) {
            const int m0 = nw * 8 + g * 4;
            float a0[4], a1[4];
            int deg[4], ent[4];
            const int* bk[4];
            int4 q[4];
            int em = 0;
            #pragma unroll
            for (int j = 0; j < 4; ++j) {
                a0[j] = 0.f; a1[j] = 0.f;
                int node = min(base + m0 + j, N_NODES - 1);  // tail rows: dup gather, never stored
                deg[j] = __builtin_amdgcn_readfirstlane(counts[node]);
                ent[j] = min(deg[j], CAP);
                em = max(em, ent[j]);
                bk[j] = (const int*)((const char*)out + (size_t)node * 512 + 256);
                q[j] = *(const int4*)(bk[j]);       // slots 0..3 (allocated; sel-guarded use)
                // own row -> hid_s[m][128:256] (coalesced; hidden among gather loads)
                unsigned self = *(const unsigned*)(ht + (size_t)node * 128 + lane * 2);
                *(unsigned*)(&hid_s[m0 + j][128 + lane * 2]) = self;
            }
            #pragma unroll 1
            for (int p = 0; p < em; p += 4) {
                int4 nx[4];
                #pragma unroll
                for (int j = 0; j < 4; ++j)
                    nx[j] = *(const int4*)(bk[j] + min(p + 4, CAP - 4));  // prefetch (sel-guarded use)
                unsigned uu[16];
                // pass 1: 16 unconditional loads; dead slots -> zero sentinel row
                #pragma unroll
                for (int k = 0; k < 4; ++k) {
                    #pragma unroll
                    for (int j = 0; j < 4; ++j) {
                        int idx = (k == 0) ? q[j].x : (k == 1) ? q[j].y
                                : (k == 2) ? q[j].z : q[j].w;
                        idx = __builtin_amdgcn_readfirstlane(idx);
                        idx = (p + k < ent[j]) ? idx : ZROW;   // scalar cselect, no branch
                        uu[k * 4 + j] = *(const unsigned*)(ht + (size_t)idx * 128 + lane * 2);
                    }
                }
                // pass 2: unconditional accumulate (sentinel adds 0.0)
                #pragma unroll
                for (int k = 0; k < 4; ++k) {
                    #pragma unroll
                    for (int j = 0; j < 4; ++j)
                        acc2(uu[k * 4 + j], a0[j], a1[j]);
                }
                #pragma unroll
                for (int j = 0; j < 4; ++j) q[j] = nx[j];
            }
            #pragma unroll
            for (int j = 0; j < 4; ++j) {
                float inv = 1.0f / (float)max(deg[j], 1);
                unsigned o = (unsigned)f2bf(a0[j] * inv) | ((unsigned)f2bf(a1[j] * inv) << 16);
                *(unsigned*)(&hid_s[m0 + j][lane * 2]) = o;
            }
        }
    }

    __syncthreads();    // gather writes (means + self rows) visible to all waves

    // ---- Layer 1: hid = A (32x256) @ W1 (256x256); A from LDS, B from L2 ---
    f32x16 c1[2];   // [nt]
    #pragma unroll
    for (int e2 = 0; e2 < 16; ++e2) { c1[0][e2] = 0.f; c1[1][e2] = 0.f; }

    #pragma unroll
    for (int c = 0; c < 4; ++c) {
        bf16x8 a0[4];
        #pragma unroll
        for (int ks = 0; ks < 4; ++ks) {
            // k 0..127 = self features (LDS col 128+), k 128..255 = means (LDS col 0+)
            int koff = (c < 2) ? (128 + c * 64 + ks * 16 + lg * 8)
                               : ((c - 2) * 64 + ks * 16 + lg * 8);
            a0[ks] = *(const bf16x8*)(&hid_s[lr][koff]);
        }
        #pragma unroll
        for (int ks = 0; ks < 4; ++ks) {
            #pragma unroll
            for (int nt = 0; nt < 2; ++nt) {
                int n = nw * 64 + nt * 32 + lr;
                bf16x8 b = *(const bf16x8*)(w1sw + c * 16384 + (((ks * 2 + lg) * 256) + n) * 8);
                c1[nt] = __builtin_amdgcn_mfma_f32_32x32x16_bf16(a0[ks], b, c1[nt], 0, 0, 0);
            }
        }
    }

    __syncthreads();    // all A reads done before epilogue-1 overwrites

    // ---- epilogue 1: + b1 -> bf16 -> hid_s (row-major [m][k]) --------------
    #pragma unroll
    for (int nt = 0; nt < 2; ++nt) {
        int col = nw * 64 + nt * 32 + lr;
        float bias = b1[col];
        #pragma unroll
        for (int reg = 0; reg < 16; ++reg) {
            int m = (reg & 3) + 8 * (reg >> 2) + 4 * lg;
            hid_s[m][col] = f2bf(c1[nt][reg] + bias);
        }
    }
    __syncthreads();    // hidden tile visible

    // ---- Layer 2: out = hid (32x256) @ W2 (256x128), B direct from global --
    f32x16 c2;
    #pragma unroll
    for (int e2 = 0; e2 < 16; ++e2) c2[e2] = 0.f;

    #pragma unroll
    for (int c = 0; c < 2; ++c) {
        #pragma unroll
        for (int ks = 0; ks < 8; ++ks) {
            bf16x8 b = *(const bf16x8*)(w2sw + c * 16384 + ((ks * 2 + lg) * 128 + nw * 32 + lr) * 8);
            int koff = c * 128 + ks * 16 + lg * 8;
            bf16x8 ah0 = *(const bf16x8*)(&hid_s[lr][koff]);
            c2 = __builtin_amdgcn_mfma_f32_32x32x16_bf16(ah0, b, c2, 0, 0, 0);
        }
    }

    // ---- epilogue 2: + b2, relu, store fp32 (clobbers own bucket rows only)
    {
        int col = nw * 32 + lr;
        float bias = b2[col];
        #pragma unroll
        for (int reg = 0; reg < 16; ++reg) {
            int m = (reg & 3) + 8 * (reg >> 2) + 4 * lg;
            int n = base + m;
            if (n < N_NODES)
                out[(size_t)n * OUT_DIM + col] = fmaxf(c2[reg] + bias, 0.0f);
        }
    }
}

extern "C" void kernel_launch(void* const* d_in, const int* in_sizes, int n_in,
                              void* d_out, int out_size, void* d_ws, size_t ws_size,
                              hipStream_t stream) {
    const float* h   = (const float*)d_in[0];
    const int*   src = (const int*)d_in[1];
    const int*   dst = (const int*)d_in[2];
    const float* W1  = (const float*)d_in[3];
    const float* b1  = (const float*)d_in[4];
    const float* W2  = (const float*)d_in[5];
    const float* b2  = (const float*)d_in[6];
    float* out = (float*)d_out;

    // ws: counts int[50000] @0 | w1sw @200000 | w2sw @331072 |
    //     ht bf16[50001][128] @396608 | hist8 u8[256][6250] @13196864
    int* counts = (int*)d_ws;
    unsigned short* w1sw = (unsigned short*)((char*)d_ws + 200000);
    unsigned short* w2sw = (unsigned short*)((char*)d_ws + 331072);
    unsigned short* ht   = (unsigned short*)((char*)d_ws + 396608);
    unsigned char*  hist8 = (unsigned char*)((char*)d_ws + 13196864);
    const size_t WS_CSR = 13196864 + (size_t)NB_HIST * RANGE_N;   // 14,796,864

    if (ws_size >= WS_CSR) {
        // Atomic-free CSR path (no memset needed at all)
        sage_prep<<<NB_PREP, 256, 0, stream>>>(
            dst, hist8, h, ht, W1, W2, w1sw, w2sw);
        sage_csr<<<NB_CSR, 256, 0, stream>>>(hist8, counts);
        sage_fill<<<NB_HIST, 256, 0, stream>>>(src, dst, hist8, (char*)d_out);
    } else {
        // Fallback: proven r8 atomic fill
        hipMemsetAsync(counts, 0, N_NODES * sizeof(int), stream);
        sage_prep_fb<<<FB_NB_PREP, 256, 0, stream>>>(
            src, dst, counts, (char*)d_out, h, ht, W1, W2, w1sw, w2sw);
    }

    sage_fused<<<NB_MLP, 256, 0, stream>>>(counts, ht, w1sw, w2sw, b1, b2, out);
}

// Round 12
// 161.006 us; speedup vs baseline: 1.3208x; 1.3208x over previous
//
#include <hip/hip_runtime.h>

#define N_NODES 50000
#define E_EDGES 600000
#define IN_DIM  128
#define HID     256
#define OUT_DIM 128
#define CAP_S   32     // per-section bucket capacity (2 sections x 32 = 64 ints = 256B d_out slot)
#define ZROW    N_NODES   // sentinel ht row of zeros (row 50000)

#define RANGE_N 6250   // N_NODES / 8 ranges (one per XCD, heuristically)
#define CHUNK_E 2048   // edges per fill block (8/thread)
#define NB_FILL 2344   // 293 chunks x 8 ranges; 293*2048 = 600064 >= E
#define NB_HCVT 3125   // N*16/256, 8 floats/thread
#define NB_WCVT 384    // (65536+32768)/256
#define NB_PREP (NB_FILL + NB_HCVT + NB_WCVT + 1)   // 5854 (last block zeroes ZROW)
#define NB_MLP  1563   // (N_NODES+31)/32  -- 32-row blocks
#define BROWS   32

typedef __bf16 bf16x8 __attribute__((ext_vector_type(8)));
typedef float  f32x16 __attribute__((ext_vector_type(16)));
typedef unsigned short ushort8 __attribute__((ext_vector_type(8)));

__device__ __forceinline__ unsigned short f2bf(float f) {
    union { float f; unsigned int i; } v; v.f = f;
    unsigned int b = v.i;
    b += 0x7fffu + ((b >> 16) & 1u);   // RNE
    return (unsigned short)(b >> 16);
}
// accumulate 2 packed bf16 (one uint) into two f32 accumulators: 4 VALU insts
__device__ __forceinline__ void acc2(unsigned u, float& a0, float& a1) {
    union { unsigned i; float f; } lo, hi;
    lo.i = u << 16; hi.i = u & 0xffff0000u;
    a0 += lo.f; a1 += hi.f;
}

// ---------------------------------------------------------------------------
// Prep: [XCD-local bucket fill, 2-way REPLICATED counters] + [h fp32->bf16]
// + [W -> swz bf16] + [zero sentinel row].
// Counter for node d is counts2[d*2 + (e&1)] -> same-address atomic chains
// halve. Bucket row stays 256B: section sec's slot i lives at int offset
// i*2+sec, so an int4 at offset 4p covers slots {2p,2p+1} of BOTH sections
// (gather masks per-section).
// Fill: block b -> range r = b&7, chunk b>>3; under round-robin block->XCD
// dispatch each bucket row + its counters are owned by one XCD's L2.
// Correct under ANY placement.
//   w1sw flat = (((c*4 + ks)*2 + g)*256 + n)*8 + j,  k = c*64 + ks*16 + g*8 + j
//   w2sw flat = (((c*8 + ks)*2 + g)*128 + n)*8 + j,  k = c*128 + ks*16 + g*8 + j
// ---------------------------------------------------------------------------
__global__ void __launch_bounds__(256)
sage_prep(const int* __restrict__ src, const int* __restrict__ dst,
          int* __restrict__ counts2, char* __restrict__ outb,
          const float* __restrict__ h, unsigned short* __restrict__ ht,
          const float* __restrict__ W1, const float* __restrict__ W2,
          unsigned short* __restrict__ w1sw, unsigned short* __restrict__ w2sw) {
    int b = blockIdx.x;
    if (b < NB_FILL) {
        int r = b & 7;
        int chunk = b >> 3;
        int e0 = chunk * CHUNK_E + threadIdx.x * 8;
        if (e0 < E_EDGES) {            // E % 8 == 0 -> whole 8-group in/out together
            int lo = r * RANGE_N, hi = lo + RANGE_N;
            const int4 d0 = *(const int4*)(dst + e0);
            const int4 d1 = *(const int4*)(dst + e0 + 4);
            int dd[8] = {d0.x, d0.y, d0.z, d0.w, d1.x, d1.y, d1.z, d1.w};
            #pragma unroll
            for (int k = 0; k < 8; ++k) {
                int d = dd[k];
                if (d >= lo && d < hi) {
                    int s = src[e0 + k];
                    int sec = k & 1;                 // (e0+k)&1 == k&1 (e0 mult of 8)
                    int sl = atomicAdd(counts2 + d * 2 + sec, 1);
                    if (sl < CAP_S)
                        *((int*)(outb + (size_t)d * 512 + 256) + sl * 2 + sec) = s;
                }
            }
        }
    } else if (b < NB_FILL + NB_HCVT) {
        int idx = (b - NB_FILL) * 256 + threadIdx.x;   // < 800000 exactly
        int n = idx >> 4, g = idx & 15;                 // 16 threads/node, 8 f/thread
        const float4 v0 = *(const float4*)(h + (size_t)n * IN_DIM + g * 8);
        const float4 v1 = *(const float4*)(h + (size_t)n * IN_DIM + g * 8 + 4);
        ushort8 o;
        o[0] = f2bf(v0.x); o[1] = f2bf(v0.y); o[2] = f2bf(v0.z); o[3] = f2bf(v0.w);
        o[4] = f2bf(v1.x); o[5] = f2bf(v1.y); o[6] = f2bf(v1.z); o[7] = f2bf(v1.w);
        *(ushort8*)(ht + (size_t)n * 128 + g * 8) = o;
    } else if (b < NB_FILL + NB_HCVT + NB_WCVT) {
        int i1 = (b - NB_FILL - NB_HCVT) * 256 + threadIdx.x;
        if (i1 < 65536) {
            int j = i1 & 7, n = (i1 >> 3) & 255, g = (i1 >> 11) & 1, ks = (i1 >> 12) & 3, c = i1 >> 14;
            int k = c * 64 + ks * 16 + g * 8 + j;
            w1sw[i1] = f2bf(W1[(size_t)k * HID + n]);
        } else {
            int i2 = i1 - 65536;
            int j = i2 & 7, n = (i2 >> 3) & 127, g = (i2 >> 10) & 1, ks = (i2 >> 11) & 7, c = (i2 >> 14) & 1;
            int k = c * 128 + ks * 16 + g * 8 + j;
            w2sw[i2] = f2bf(W2[(size_t)k * OUT_DIM + n]);
        }
    } else {
        // zero the sentinel row (ht row ZROW = 50000): dead gather slots load it
        if (threadIdx.x < 64)
            *(unsigned*)(ht + (size_t)ZROW * 128 + threadIdx.x * 2) = 0u;
    }
}

// ---------------------------------------------------------------------------
// Fused gather + 2-layer MLP — 32-row blocks, 8 blocks/CU (the gather sits at
// the chip's ~35 G-lines/s random-fetch ceiling, confirmed by four
// structurally different gathers converging there).
// Gather with sectioned buckets: per node j the counters give ent0/ent1
// (scalar, readfirstlane'd); iteration p consumes the int4 at offset 4p =
// slots {2p,2p+1} of both sections, with per-component scalar cselect masks
// (2p+i < ent_sec) -> straight-line, 16 loads in flight.
// Self rows copied to hid_s[m][128:256]; means to hid_s[m][0:128].
// Layouts: A[m=lane&31][k=(lane>>5)*8+j], B[k][n=lane&31],
//   C/D col=lane&31, row=(reg&3)+8*(reg>>2)+4*(lane>>5).
// Bucket rows (d_out, node n at n*512+256) are read before the same block's
// fp32 out write clobbers row n's 512B: reads precede first barrier, stores
// after 3 barriers; only the owning block touches row n's bytes.
// ---------------------------------------------------------------------------
__global__ void __launch_bounds__(256, 8)
sage_fused(const int* __restrict__ counts2,
           const unsigned short* __restrict__ ht,     // ws: bf16 [N+1][128]
           const unsigned short* __restrict__ w1sw,
           const unsigned short* __restrict__ w2sw,
           const float* __restrict__ b1,
           const float* __restrict__ b2,
           float* out) {                              // d_out (also holds bucket)
    __shared__ unsigned short hid_s[BROWS][264];  // 16.9 KB: [0:128)=means, [128:256)=self

    const int t = threadIdx.x;
    const int nw = t >> 6;
    const int lane = t & 63;
    const int lr = lane & 31;
    const int lg = lane >> 5;
    const int base = blockIdx.x * BROWS;

    // ---- Phase G: branch-free coalesced gather, 8 nodes/wave (2 groups) ----
    {
        #pragma unroll 1
        for (int g = 0; g < 2; ++g) {
            const int m0 = nw * 8 + g * 4;
            float a0[4], a1[4];
            int deg[4], e0n[4], e1n[4];
            const int* bk[4];
            int4 q[4];
            int em = 1;
            #pragma unroll
            for (int j = 0; j < 4; ++j) {
                a0[j] = 0.f; a1[j] = 0.f;
                int node = min(base + m0 + j, N_NODES - 1);  // tail rows: dup gather, never stored
                int c0 = __builtin_amdgcn_readfirstlane(counts2[node * 2]);
                int c1 = __builtin_amdgcn_readfirstlane(counts2[node * 2 + 1]);
                deg[j] = c0 + c1;
                e0n[j] = min(c0, CAP_S);
                e1n[j] = min(c1, CAP_S);
                em = max(em, max(e0n[j], e1n[j]));
                bk[j] = (const int*)((const char*)out + (size_t)node * 512 + 256);
                q[j] = *(const int4*)(bk[j]);       // slots {0,1}x{s0,s1} (sel-guarded use)
                // own row -> hid_s[m][128:256] (coalesced; hidden among gather loads)
                unsigned self = *(const unsigned*)(ht + (size_t)node * 128 + lane * 2);
                *(unsigned*)(&hid_s[m0 + j][128 + lane * 2]) = self;
            }
            #pragma unroll 1
            for (int p = 0; 2 * p < em; ++p) {
                int4 nx[4];
                #pragma unroll
                for (int j = 0; j < 4; ++j)
                    nx[j] = *(const int4*)(bk[j] + min(p + 1, 15) * 4);  // prefetch (sel-guarded)
                unsigned uu[16];
                // pass 1: 16 unconditional loads; dead slots -> zero sentinel row
                // component k: {k0: slot 2p sec0, k1: slot 2p sec1,
                //               k2: slot 2p+1 sec0, k3: slot 2p+1 sec1}
                #pragma unroll
                for (int k = 0; k < 4; ++k) {
                    #pragma unroll
                    for (int j = 0; j < 4; ++j) {
                        int idx = (k == 0) ? q[j].x : (k == 1) ? q[j].y
                                : (k == 2) ? q[j].z : q[j].w;
                        idx = __builtin_amdgcn_readfirstlane(idx);
                        int slot = 2 * p + (k >> 1);
                        int ent  = (k & 1) ? e1n[j] : e0n[j];
                        idx = (slot < ent) ? idx : ZROW;   // scalar cselect, no branch
                        uu[k * 4 + j] = *(const unsigned*)(ht + (size_t)idx * 128 + lane * 2);
                    }
                }
                // pass 2: unconditional accumulate (sentinel adds 0.0)
                #pragma unroll
                for (int k = 0; k < 4; ++k) {
                    #pragma unroll
                    for (int j = 0; j < 4; ++j)
                        acc2(uu[k * 4 + j], a0[j], a1[j]);
                }
                #pragma unroll
                for (int j = 0; j < 4; ++j) q[j] = nx[j];
            }
            #pragma unroll
            for (int j = 0; j < 4; ++j) {
                float inv = 1.0f / (float)max(deg[j], 1);
                unsigned o = (unsigned)f2bf(a0[j] * inv) | ((unsigned)f2bf(a1[j] * inv) << 16);
                *(unsigned*)(&hid_s[m0 + j][lane * 2]) = o;
            }
        }
    }

    __syncthreads();    // gather writes (means + self rows) visible to all waves

    // ---- Layer 1: hid = A (32x256) @ W1 (256x256); A from LDS, B from L2 ---
    f32x16 c1[2];   // [nt]
    #pragma unroll
    for (int e2 = 0; e2 < 16; ++e2) { c1[0][e2] = 0.f; c1[1][e2] = 0.f; }

    #pragma unroll
    for (int c = 0; c < 4; ++c) {
        bf16x8 a0[4];
        #pragma unroll
        for (int ks = 0; ks < 4; ++ks) {
            // k 0..127 = self features (LDS col 128+), k 128..255 = means (LDS col 0+)
            int koff = (c < 2) ? (128 + c * 64 + ks * 16 + lg * 8)
                               : ((c - 2) * 64 + ks * 16 + lg * 8);
            a0[ks] = *(const bf16x8*)(&hid_s[lr][koff]);
        }
        #pragma unroll
        for (int ks = 0; ks < 4; ++ks) {
            #pragma unroll
            for (int nt = 0; nt < 2; ++nt) {
                int n = nw * 64 + nt * 32 + lr;
                bf16x8 b = *(const bf16x8*)(w1sw + c * 16384 + (((ks * 2 + lg) * 256) + n) * 8);
                c1[nt] = __builtin_amdgcn_mfma_f32_32x32x16_bf16(a0[ks], b, c1[nt], 0, 0, 0);
            }
        }
    }

    __syncthreads();    // all A reads done before epilogue-1 overwrites

    // ---- epilogue 1: + b1 -> bf16 -> hid_s (row-major [m][k]) --------------
    #pragma unroll
    for (int nt = 0; nt < 2; ++nt) {
        int col = nw * 64 + nt * 32 + lr;
        float bias = b1[col];
        #pragma unroll
        for (int reg = 0; reg < 16; ++reg) {
            int m = (reg & 3) + 8 * (reg >> 2) + 4 * lg;
            hid_s[m][col] = f2bf(c1[nt][reg] + bias);
        }
    }
    __syncthreads();    // hidden tile visible

    // ---- Layer 2: out = hid (32x256) @ W2 (256x128), B direct from global --
    f32x16 c2;
    #pragma unroll
    for (int e2 = 0; e2 < 16; ++e2) c2[e2] = 0.f;

    #pragma unroll
    for (int c = 0; c < 2; ++c) {
        #pragma unroll
        for (int ks = 0; ks < 8; ++ks) {
            bf16x8 b = *(const bf16x8*)(w2sw + c * 16384 + ((ks * 2 + lg) * 128 + nw * 32 + lr) * 8);
            int koff = c * 128 + ks * 16 + lg * 8;
            bf16x8 ah0 = *(const bf16x8*)(&hid_s[lr][koff]);
            c2 = __builtin_amdgcn_mfma_f32_32x32x16_bf16(ah0, b, c2, 0, 0, 0);
        }
    }

    // ---- epilogue 2: + b2, relu, store fp32 (clobbers own bucket rows only)
    {
        int col = nw * 32 + lr;
        float bias = b2[col];
        #pragma unroll
        for (int reg = 0; reg < 16; ++reg) {
            int m = (reg & 3) + 8 * (reg >> 2) + 4 * lg;
            int n = base + m;
            if (n < N_NODES)
                out[(size_t)n * OUT_DIM + col] = fmaxf(c2[reg] + bias, 0.0f);
        }
    }
}

extern "C" void kernel_launch(void* const* d_in, const int* in_sizes, int n_in,
                              void* d_out, int out_size, void* d_ws, size_t ws_size,
                              hipStream_t stream) {
    const float* h   = (const float*)d_in[0];
    const int*   src = (const int*)d_in[1];
    const int*   dst = (const int*)d_in[2];
    const float* W1  = (const float*)d_in[3];
    const float* b1  = (const float*)d_in[4];
    const float* W2  = (const float*)d_in[5];
    const float* b2  = (const float*)d_in[6];
    float* out = (float*)d_out;

    // ws: counts2 [100000 int] | w1sw [65536 bf16] | w2sw [32768 bf16] |
    //     ht [50001 x 128 bf16]  (row 50000 = zero sentinel)
    // total ~13.4 MB (bucket lives in d_out).
    int* counts2 = (int*)d_ws;
    unsigned short* w1sw = (unsigned short*)(counts2 + 2 * N_NODES);
    unsigned short* w2sw = w1sw + 65536;
    unsigned short* ht   = w2sw + 32768;   // 16B aligned

    hipMemsetAsync(counts2, 0, 2 * N_NODES * sizeof(int), stream);

    sage_prep<<<NB_PREP, 256, 0, stream>>>(
        src, dst, counts2, (char*)d_out, h, ht, W1, W2, w1sw, w2sw);

    sage_fused<<<NB_MLP, 256, 0, stream>>>(counts2, ht, w1sw, w2sw, b1, b2, out);
}